// Round 1
// baseline (1569.198 us; speedup 1.0000x reference)
//
#include <hip/hip_runtime.h>
#include <hip/hip_fp16.h>
#include <cstdio>

typedef unsigned short u16;
typedef __attribute__((ext_vector_type(8))) _Float16 f16x8;
typedef __attribute__((ext_vector_type(4))) float fv4;

#define TT 512
#define BB 256

__device__ __forceinline__ float us2f(u16 u) {
    union { u16 u; _Float16 h; } c; c.u = u; return (float)c.h;
}
__device__ __forceinline__ u16 f2us(float f) {
    union { u16 u; _Float16 h; } c; c.h = (_Float16)f; return c.u;
}

// async global->LDS, 16B per lane. LDS dest must be wave-uniform base + lane*16.
__device__ __forceinline__ void gl_lds16(const u16* g, u16* l) {
    __builtin_amdgcn_global_load_lds(
        (const __attribute__((address_space(1))) void*)g,
        (__attribute__((address_space(3))) void*)l, 16, 0, 0);
}

// ---------------- fp32 -> fp16 convert (n % 8 == 0) ----------------
__global__ void cvt_f32_f16(const float* __restrict__ s, u16* __restrict__ d, int n) {
    long stride = (long)gridDim.x * blockDim.x * 8;
    for (long i = ((long)blockIdx.x * blockDim.x + threadIdx.x) * 8; i < n; i += stride) {
        f16x8 o;
#pragma unroll
        for (int j = 0; j < 8; ++j) o[j] = (_Float16)s[i + j];
        *(f16x8*)(d + i) = o;
    }
}

// ---------------- bias fold: bsum = b_ih + (j<512 ? b_hh : 0) ----------------
__global__ void bias_fold(const float* __restrict__ bih, const float* __restrict__ bhh,
                          float* __restrict__ bsum) {
    int i = blockIdx.x * blockDim.x + threadIdx.x;
    if (i < 768) bsum[i] = bih[i] + (i < 512 ? bhh[i] : 0.f);
}

// ---------------- pack W_hh [768,256] into MFMA B-frag order ----------------
// Wp[((jt*8 + kt)*64 + lane)*8 + i] = Whh[jt*16 + (lane&15)][kt*32 + (lane>>4)*8 + i]
__global__ void pack_whh(const float* __restrict__ W, u16* __restrict__ Wp) {
    int t = blockIdx.x * blockDim.x + threadIdx.x;   // 0..24575
    int l = t & 63;
    int kt = (t >> 6) & 7;
    int jt = t >> 9;                                  // 0..47
    int j = jt * 16 + (l & 15);
    int k = kt * 32 + (l >> 4) * 8;
    f16x8 o;
#pragma unroll
    for (int i = 0; i < 8; ++i) o[i] = (_Float16)W[j * 256 + k + i];
    *(f16x8*)(Wp + (size_t)t * 8) = o;
}

// ---------------- pack W2b [18,512] zero-padded to [32,512] in B-frag order --
__global__ void pack_w2b(const float* __restrict__ W, u16* __restrict__ Wp) {
    int t = blockIdx.x * blockDim.x + threadIdx.x;   // 0..2047
    int l = t & 63;
    int kt = (t >> 6) & 15;
    int nt = t >> 10;                                 // 0..1
    int n = nt * 16 + (l & 15);
    int k = kt * 32 + (l >> 4) * 8;
    f16x8 o;
#pragma unroll
    for (int i = 0; i < 8; ++i)
        o[i] = (n < 18) ? (_Float16)W[n * 512 + k + i] : (_Float16)0.f;
    *(f16x8*)(Wp + (size_t)t * 8) = o;
}

// ---------------- generic fp16 GEMM: C[m,n] = act(sum_k A[m,k]*B[n,k] + bias[n])
__global__ __launch_bounds__(256) void gemm_bt(
    const u16* __restrict__ A, const u16* __restrict__ B,
    const float* __restrict__ bias, u16* __restrict__ C,
    int N, int K, int act)
{
    __shared__ u16 Ash[4096] __attribute__((aligned(16)));
    __shared__ u16 Bsh[4096] __attribute__((aligned(16)));
    const int tid = threadIdx.x;
    const int l = tid & 63, w = tid >> 6;
    const long m0 = (long)blockIdx.y * 128;
    const int n0 = blockIdx.x * 128;
    const int r = tid >> 2, c8 = (tid & 3) * 8;
    const u16* gA0 = A + (m0 + r) * K + c8;
    const u16* gA1 = A + (m0 + 64 + r) * K + c8;
    const u16* gB0 = B + (long)(n0 + r) * K + c8;
    const u16* gB1 = B + (long)(n0 + 64 + r) * K + c8;
    const int mb = (w >> 1) * 64, nb = (w & 1) * 64;
    const int mrow = l & 15, colq = (l >> 4) * 8;
    fv4 acc[4][4] = {};
    for (int k0 = 0; k0 < K; k0 += 32) {
        gl_lds16(gA0 + k0, &Ash[tid * 8]);
        gl_lds16(gA1 + k0, &Ash[2048 + tid * 8]);
        gl_lds16(gB0 + k0, &Bsh[tid * 8]);
        gl_lds16(gB1 + k0, &Bsh[2048 + tid * 8]);
        __syncthreads();
        f16x8 af[4], bf[4];
#pragma unroll
        for (int i = 0; i < 4; ++i)
            af[i] = *(const f16x8*)&Ash[(mb + i * 16 + mrow) * 32 + colq];
#pragma unroll
        for (int i = 0; i < 4; ++i)
            bf[i] = *(const f16x8*)&Bsh[(nb + i * 16 + mrow) * 32 + colq];
#pragma unroll
        for (int mt = 0; mt < 4; ++mt)
#pragma unroll
            for (int nt = 0; nt < 4; ++nt)
                acc[mt][nt] = __builtin_amdgcn_mfma_f32_16x16x32_f16(
                    af[mt], bf[nt], acc[mt][nt], 0, 0, 0);
        __syncthreads();
    }
    float bv[4];
#pragma unroll
    for (int nt = 0; nt < 4; ++nt) bv[nt] = bias[n0 + nb + nt * 16 + mrow];
    const int rq = (l >> 4) * 4;
#pragma unroll
    for (int mt = 0; mt < 4; ++mt)
#pragma unroll
        for (int nt = 0; nt < 4; ++nt)
#pragma unroll
            for (int i = 0; i < 4; ++i) {
                float v = acc[mt][nt][i] + bv[nt];
                if (act) v = fmaxf(v, 0.f);
                C[(m0 + mb + mt * 16 + rq + i) * (long)N + (n0 + nb + nt * 16 + mrow)] = f2us(v);
            }
}

// ---------------- GI GEMM (N=768, K=256): stores into gru-packed layout -------
// GIp[((((t*16+blk)*8 + w)*64 + lane)*24 + u*4 + i] ; u = gate*2 + s
__global__ __launch_bounds__(256) void gemm_gi(
    const u16* __restrict__ A, const u16* __restrict__ B,
    const float* __restrict__ bias, u16* __restrict__ GIp)
{
    __shared__ u16 Ash[4096] __attribute__((aligned(16)));
    __shared__ u16 Bsh[4096] __attribute__((aligned(16)));
    const int tid = threadIdx.x;
    const int l = tid & 63, w = tid >> 6;
    const long m0 = (long)blockIdx.y * 128;
    const int n0 = blockIdx.x * 128;
    const int r = tid >> 2, c8 = (tid & 3) * 8;
    const u16* gA0 = A + (m0 + r) * 256 + c8;
    const u16* gA1 = A + (m0 + 64 + r) * 256 + c8;
    const u16* gB0 = B + (long)(n0 + r) * 256 + c8;
    const u16* gB1 = B + (long)(n0 + 64 + r) * 256 + c8;
    const int mb = (w >> 1) * 64, nb = (w & 1) * 64;
    const int mrow = l & 15, colq = (l >> 4) * 8;
    fv4 acc[4][4] = {};
    for (int k0 = 0; k0 < 256; k0 += 32) {
        gl_lds16(gA0 + k0, &Ash[tid * 8]);
        gl_lds16(gA1 + k0, &Ash[2048 + tid * 8]);
        gl_lds16(gB0 + k0, &Bsh[tid * 8]);
        gl_lds16(gB1 + k0, &Bsh[2048 + tid * 8]);
        __syncthreads();
        f16x8 af[4], bf[4];
#pragma unroll
        for (int i = 0; i < 4; ++i)
            af[i] = *(const f16x8*)&Ash[(mb + i * 16 + mrow) * 32 + colq];
#pragma unroll
        for (int i = 0; i < 4; ++i)
            bf[i] = *(const f16x8*)&Bsh[(nb + i * 16 + mrow) * 32 + colq];
#pragma unroll
        for (int mt = 0; mt < 4; ++mt)
#pragma unroll
            for (int nt = 0; nt < 4; ++nt)
                acc[mt][nt] = __builtin_amdgcn_mfma_f32_16x16x32_f16(
                    af[mt], bf[nt], acc[mt][nt], 0, 0, 0);
        __syncthreads();
    }
    float bv[4];
#pragma unroll
    for (int nt = 0; nt < 4; ++nt) bv[nt] = bias[n0 + nb + nt * 16 + mrow];
    const int rq = (l >> 4) * 4;
#pragma unroll
    for (int mt = 0; mt < 4; ++mt)
#pragma unroll
        for (int nt = 0; nt < 4; ++nt)
#pragma unroll
            for (int i = 0; i < 4; ++i) {
                float v = acc[mt][nt][i] + bv[nt];
                int m = (int)(m0 + mb + mt * 16 + rq + i);
                int n = n0 + nb + nt * 16 + mrow;
                int t  = m >> 8, b = m & 255;
                int blk = b >> 4, rb = b & 15, q = rb >> 2, i2 = rb & 3;
                int g = n >> 8, c = n & 255, w2 = c >> 5, s = (c >> 4) & 1, cl = c & 15;
                size_t idx = ((((size_t)t * 16 + blk) * 8 + w2) * 64 + (q * 16 + cl)) * 24
                             + (g * 2 + s) * 4 + i2;
                GIp[idx] = f2us(v);
            }
}

// ---------------- sequential GRU v5 ------------------------------------------
// Round-4 diagnosis: v4 showed VGPR_Count=128 -> the 42-fragment hoist FAILED;
// every wave re-issued ~42 global_load_dwordx4 + addr VALU per step (active-CU
// VALUBusy ~62%). Fix: (a) kt 6,7 both in LDS (Wl 96KB, wf drops to 36 frags =
// 144 VGPRs, total need ~220 < 256 cap), (b) asm "+v" pins make the fragments
// non-rematerializable so LLVM CANNOT sink them (spill would show as scratch;
// headroom says it won't). (c) Hout now written as ONE packed f16x8 store per
// lane per step (A-frag layout, read back from h_sh) instead of 8 scalar
// global_store_short -> the pre-barrier vmcnt(0) drain retires long before.
// Verification: VGPR_Count must be ~220+, localMem must be 0.
__global__ __launch_bounds__(512, 2) void gru_seq5(
    const u16* __restrict__ Wp, const u16* __restrict__ GIp,
    const float* __restrict__ bhh, u16* __restrict__ Hp)
{
    __shared__ u16 h_sh[2][4096] __attribute__((aligned(16)));  // dbuf h (A-frag layout)
    __shared__ u16 Wl[49152] __attribute__((aligned(16)));      // kt 6,7: [2][48][64][8]
    const int tid = threadIdx.x;
    const int l = tid & 63, w = tid >> 6;
    const int blk = blockIdx.x;
    const int col = l & 15, quad = l >> 4;

    for (int i = tid; i < 4096; i += 512) h_sh[0][i] = 0;
    for (int idx = tid; idx < 6144; idx += 512) {
        int kt6 = idx / 3072, rem = idx % 3072;       // jt = rem>>6, lane = rem&63
        *(f16x8*)&Wl[(size_t)idx * 8] =
            *(const f16x8*)&Wp[(((size_t)(rem >> 6) * 8 + 6 + kt6) * 64 + (rem & 63)) * 8];
    }

    int jts[6];
#pragma unroll
    for (int g = 0; g < 3; ++g)
#pragma unroll
        for (int s = 0; s < 2; ++s) jts[g * 2 + s] = g * 16 + 2 * w + s;

    // W_hh fragments kt 0..5: 36 f16x8 = 144 VGPRs, loop-invariant.
    f16x8 wf[6][6];
#pragma unroll
    for (int u = 0; u < 6; ++u)
#pragma unroll
        for (int kt = 0; kt < 6; ++kt)
            wf[u][kt] = *(const f16x8*)&Wp[(((size_t)jts[u] * 8 + kt) * 64 + l) * 8];
    // Pin: asm output is not rematerializable -> fragments must stay live in VGPRs.
#pragma unroll
    for (int u = 0; u < 6; ++u)
#pragma unroll
        for (int kt = 0; kt < 6; ++kt)
            asm volatile("" : "+v"(wf[u][kt]));

    float hbn[2] = { bhh[512 + 32 * w + col], bhh[512 + 32 * w + 16 + col] };

    const u16* gbase = GIp + ((size_t)(blk * 8 + w) * 64 + l) * 24;
    f16x8 gcur[3], gnxt[3];
#pragma unroll
    for (int j = 0; j < 3; ++j) gcur[j] = *(const f16x8*)(gbase + j * 8);

    float hold[2][4] = {};
    u16* hp_base = Hp + (size_t)blk * 4096 + tid * 8;   // packed A-frag layout
    __syncthreads();

    for (int t = 0; t < TT; ++t) {
        const int rd = t & 1, wr = (t + 1) & 1;
        // store h_t (finished last step) as one 16B packed store; Hout[t-1] = h_t
        if (t) {
            f16x8 hv = *(const f16x8*)&h_sh[rd][tid * 8];
            *(f16x8*)(hp_base + (size_t)(t - 1) * 65536) = hv;
        }
        // prefetch next step's gi (full step of latency cover)
        const u16* gn = gbase + (size_t)(t < TT - 1 ? t + 1 : t) * 196608;
#pragma unroll
        for (int j = 0; j < 3; ++j) gnxt[j] = *(const f16x8*)(gn + j * 8);

        fv4 acc[6] = {};
#pragma unroll
        for (int kt = 0; kt < 6; ++kt) {
            f16x8 a = *(const f16x8*)&h_sh[rd][(kt * 64 + l) * 8];
#pragma unroll
            for (int u = 0; u < 6; ++u)
                acc[u] = __builtin_amdgcn_mfma_f32_16x16x32_f16(a, wf[u][kt], acc[u], 0, 0, 0);
        }
#pragma unroll
        for (int kt6 = 0; kt6 < 2; ++kt6) {
            f16x8 a = *(const f16x8*)&h_sh[rd][((6 + kt6) * 64 + l) * 8];
#pragma unroll
            for (int u = 0; u < 6; ++u) {
                f16x8 bw = *(const f16x8*)&Wl[((size_t)(kt6 * 48 + jts[u]) * 64 + l) * 8];
                acc[u] = __builtin_amdgcn_mfma_f32_16x16x32_f16(a, bw, acc[u], 0, 0, 0);
            }
        }
        // epilogue: gates + h update (writes OTHER h buffer -> one barrier/step)
#pragma unroll
        for (int s = 0; s < 2; ++s) {
            const int q2 = s * 2 + (col >> 3);
#pragma unroll
            for (int i = 0; i < 4; ++i) {
                float pr  = (float)gcur[0][s * 4 + i] + acc[0 + s][i];   // biases folded
                float pz  = (float)gcur[1][s * 4 + i] + acc[2 + s][i];
                float h_n = acc[4 + s][i] + hbn[s];
                float rg = __builtin_amdgcn_rcpf(1.f + __expf(-pr));
                float zg = __builtin_amdgcn_rcpf(1.f + __expf(-pz));
                float pre = (float)gcur[2][s * 4 + i] + rg * h_n;
                float ea = __expf(-2.f * fabsf(pre));
                float th = (1.f - ea) * __builtin_amdgcn_rcpf(1.f + ea);
                float ng = (pre >= 0.f) ? th : -th;
                float hn = (1.f - zg) * ng + zg * hold[s][i];
                hold[s][i] = hn;
                h_sh[wr][(w * 64 + q2 * 16 + quad * 4 + i) * 8 + (col & 7)] = f2us(hn);
            }
        }
#pragma unroll
        for (int j = 0; j < 3; ++j) gcur[j] = gnxt[j];
        __syncthreads();
    }
    // final h_512 lives in buffer (TT)&1 == 0 -> Hout[511]
    {
        f16x8 hv = *(const f16x8*)&h_sh[0][tid * 8];
        *(f16x8*)(hp_base + (size_t)511 * 65536) = hv;
    }
}

// ---------------- Phase-B GEMM from packed Hp: C = relu(Hp @ W2a^T + b2a) -----
// A-fragments come straight from global (already MFMA A-frag order), no A
// staging. B staged via gl_lds16 as usual. N=512, K=256 fixed.
__global__ __launch_bounds__(256) void gemm_hp(
    const u16* __restrict__ Hp, const u16* __restrict__ B,
    const float* __restrict__ bias, u16* __restrict__ C)
{
    __shared__ u16 Bsh[4096] __attribute__((aligned(16)));
    const int tid = threadIdx.x;
    const int l = tid & 63, w = tid >> 6;
    const long m0 = (long)blockIdx.y * 128;
    const int n0 = blockIdx.x * 128;
    const int r = tid >> 2, c8 = (tid & 3) * 8;
    const u16* gB0 = B + (long)(n0 + r) * 256 + c8;
    const u16* gB1 = B + (long)(n0 + 64 + r) * 256 + c8;
    const int mb = (w >> 1) * 64, nb = (w & 1) * 64;
    const int mrow = l & 15, colq = (l >> 4) * 8;
    const int t = (int)(m0 >> 8), half = ((int)m0 >> 7) & 1;
    // row-tile mt (16 rows) -> blk16 = half*8 + mb/16 + mt ; frag at [kt*64+l]*8
    const u16* aBase = Hp + ((size_t)t * 16 + half * 8 + (mb >> 4)) * 4096 + (size_t)l * 8;
    fv4 acc[4][4] = {};
    for (int k0 = 0; k0 < 256; k0 += 32) {
        gl_lds16(gB0 + k0, &Bsh[tid * 8]);
        gl_lds16(gB1 + k0, &Bsh[2048 + tid * 8]);
        const int kt = k0 >> 5;
        f16x8 af[4];
#pragma unroll
        for (int i = 0; i < 4; ++i)
            af[i] = *(const f16x8*)(aBase + (size_t)i * 4096 + kt * 512);
        __syncthreads();
        f16x8 bf[4];
#pragma unroll
        for (int i = 0; i < 4; ++i)
            bf[i] = *(const f16x8*)&Bsh[(nb + i * 16 + mrow) * 32 + colq];
#pragma unroll
        for (int mt = 0; mt < 4; ++mt)
#pragma unroll
            for (int nt = 0; nt < 4; ++nt)
                acc[mt][nt] = __builtin_amdgcn_mfma_f32_16x16x32_f16(
                    af[mt], bf[nt], acc[mt][nt], 0, 0, 0);
        __syncthreads();
    }
    float bv[4];
#pragma unroll
    for (int nt = 0; nt < 4; ++nt) bv[nt] = bias[n0 + nb + nt * 16 + mrow];
    const int rq = (l >> 4) * 4;
#pragma unroll
    for (int mt = 0; mt < 4; ++mt)
#pragma unroll
        for (int nt = 0; nt < 4; ++nt)
#pragma unroll
            for (int i = 0; i < 4; ++i) {
                float v = fmaxf(acc[mt][nt][i] + bv[nt], 0.f);
                C[(m0 + mb + mt * 16 + rq + i) * 512L + (n0 + nb + nt * 16 + mrow)] = f2us(v);
            }
}

// ---------------- head: out[m, 0..17] = Q1[m,:512] @ W2b^T + b2b (fp32 out) ---
__global__ __launch_bounds__(256) void head_gemm(
    const u16* __restrict__ Q1, const u16* __restrict__ W2p,
    const float* __restrict__ b2, float* __restrict__ out)
{
    __shared__ u16 Ash[4096] __attribute__((aligned(16)));
    __shared__ u16 Bsh[16384] __attribute__((aligned(16)));
    const int tid = threadIdx.x;
    const int l = tid & 63, w = tid >> 6;
    const long m0 = (long)blockIdx.x * 128;
    const int col = l & 15, quad = l >> 4, colq = quad * 8;
    for (int i = tid * 8; i < 16384; i += 2048)
        *(f16x8*)&Bsh[i] = *(const f16x8*)&W2p[i];
    const int r = tid >> 2, c8 = (tid & 3) * 8;
    const u16* gA0 = Q1 + (m0 + r) * 512 + c8;
    const u16* gA1 = Q1 + (m0 + 64 + r) * 512 + c8;
    fv4 acc[2][2] = {};
    for (int k0 = 0; k0 < 512; k0 += 32) {
        gl_lds16(gA0 + k0, &Ash[tid * 8]);
        gl_lds16(gA1 + k0, &Ash[2048 + tid * 8]);
        __syncthreads();
        const int kt = k0 >> 5;
        f16x8 af[2], bf[2];
#pragma unroll
        for (int mt = 0; mt < 2; ++mt)
            af[mt] = *(const f16x8*)&Ash[(w * 32 + mt * 16 + col) * 32 + colq];
#pragma unroll
        for (int nt = 0; nt < 2; ++nt)
            bf[nt] = *(const f16x8*)&Bsh[((nt * 16 + kt) * 64 + l) * 8];
#pragma unroll
        for (int mt = 0; mt < 2; ++mt)
#pragma unroll
            for (int nt = 0; nt < 2; ++nt)
                acc[mt][nt] = __builtin_amdgcn_mfma_f32_16x16x32_f16(
                    af[mt], bf[nt], acc[mt][nt], 0, 0, 0);
        __syncthreads();
    }
    const int rq = quad * 4;
#pragma unroll
    for (int nt = 0; nt < 2; ++nt) {
        int c = nt * 16 + col;
        if (c < 18) {
            float bias = b2[c];
#pragma unroll
            for (int mt = 0; mt < 2; ++mt)
#pragma unroll
                for (int i = 0; i < 4; ++i)
                    out[(m0 + w * 32 + mt * 16 + rq + i) * 18 + c] = acc[mt][nt][i] + bias;
        }
    }
}

extern "C" void kernel_launch(void* const* d_in, const int* in_sizes, int n_in,
                              void* d_out, int out_size, void* d_ws, size_t ws_size,
                              hipStream_t stream) {
    const float* x   = (const float*)d_in[0];
    const float* W1a = (const float*)d_in[1];
    const float* b1a = (const float*)d_in[2];
    const float* W1b = (const float*)d_in[3];
    const float* b1b = (const float*)d_in[4];
    const float* Wih = (const float*)d_in[5];
    const float* bih = (const float*)d_in[6];
    const float* Whh = (const float*)d_in[7];
    const float* bhh = (const float*)d_in[8];
    const float* W2a = (const float*)d_in[9];
    const float* b2a = (const float*)d_in[10];
    const float* W2b = (const float*)d_in[11];
    const float* b2b = (const float*)d_in[12];

    char* ws = (char*)d_ws;
    u16* R    = (u16*)ws;                 // A1 [131072,512]f16, then GIp packed
    u16* A2b  = (u16*)(ws + 201326592);   // 67108864 B
    u16* XH   = (u16*)(ws + 268435456);   // 67108864 B (x fp16, later Hp packed)
    float* bsum = (float*)(ws + 268435456 + 67108864 - 4096);
    u16* W1ah = (u16*)(ws + 335544320);   //   262144 B
    u16* W1bh = (u16*)(ws + 335806464);   //   262144 B
    u16* Wihh = (u16*)(ws + 336068608);   //   393216 B
    u16* W2ah = (u16*)(ws + 336461824);   //   262144 B
    u16* Wpk  = (u16*)(ws + 336723968);   //   393216 B
    u16* W2p  = (u16*)(ws + 337117184);   //    32768 B
    if (ws_size < 337149952) {
        fprintf(stderr, "kernel_launch: ws too small (%zu < 337149952)\n", ws_size);
    }

    cvt_f32_f16<<<dim3(2048), dim3(256), 0, stream>>>(x, XH, 33554432);
    cvt_f32_f16<<<dim3(64), dim3(256), 0, stream>>>(W1a, W1ah, 131072);
    cvt_f32_f16<<<dim3(64), dim3(256), 0, stream>>>(W1b, W1bh, 131072);
    cvt_f32_f16<<<dim3(96), dim3(256), 0, stream>>>(Wih, Wihh, 196608);
    cvt_f32_f16<<<dim3(64), dim3(256), 0, stream>>>(W2a, W2ah, 131072);
    pack_whh<<<dim3(96), dim3(256), 0, stream>>>(Whh, Wpk);
    pack_w2b<<<dim3(8), dim3(256), 0, stream>>>(W2b, W2p);

    // Phase A
    gemm_bt<<<dim3(4, 1024), dim3(256), 0, stream>>>(XH, W1ah, b1a, R,   512, 256, 1);
    bias_fold<<<dim3(3), dim3(256), 0, stream>>>(bih, bhh, bsum);
    gemm_bt<<<dim3(2, 1024), dim3(256), 0, stream>>>(R,  W1bh, b1b, A2b, 256, 512, 1);
    gemm_gi<<<dim3(6, 1024), dim3(256), 0, stream>>>(A2b, Wihh, bsum, R);
    // Phase R: sequential GRU (writes Hp packed A-frag layout into XH region)
    gru_seq5<<<dim3(16), dim3(512), 0, stream>>>(Wpk, R, bhh, XH);
    // Phase B
    gemm_hp<<<dim3(4, 1024), dim3(256), 0, stream>>>(XH, W2ah, b2a, R);
    head_gemm<<<dim3(1024), dim3(256), 0, stream>>>(R, W2p, b2b, (float*)d_out);
}

// Round 4
// 1392.168 us; speedup vs baseline: 1.1272x; 1.1272x over previous
//
#include <hip/hip_runtime.h>
#include <hip/hip_fp16.h>
#include <cstdio>

typedef unsigned short u16;
typedef __attribute__((ext_vector_type(8))) _Float16 f16x8;
typedef __attribute__((ext_vector_type(4))) _Float16 f16x4;
typedef __attribute__((ext_vector_type(4))) float fv4;

#define TT 512
#define BB 256

__device__ __forceinline__ float us2f(u16 u) {
    union { u16 u; _Float16 h; } c; c.u = u; return (float)c.h;
}
__device__ __forceinline__ u16 f2us(float f) {
    union { u16 u; _Float16 h; } c; c.h = (_Float16)f; return c.u;
}

// async global->LDS, 16B per lane. LDS dest must be wave-uniform base + lane*16.
__device__ __forceinline__ void gl_lds16(const u16* g, u16* l) {
    __builtin_amdgcn_global_load_lds(
        (const __attribute__((address_space(1))) void*)g,
        (__attribute__((address_space(3))) void*)l, 16, 0, 0);
}

// ---------------- fp32 -> fp16 convert (n % 8 == 0) ----------------
__global__ void cvt_f32_f16(const float* __restrict__ s, u16* __restrict__ d, int n) {
    long stride = (long)gridDim.x * blockDim.x * 8;
    for (long i = ((long)blockIdx.x * blockDim.x + threadIdx.x) * 8; i < n; i += stride) {
        f16x8 o;
#pragma unroll
        for (int j = 0; j < 8; ++j) o[j] = (_Float16)s[i + j];
        *(f16x8*)(d + i) = o;
    }
}

// ---------------- bias fold: bsum = b_ih + (j<512 ? b_hh : 0) ----------------
__global__ void bias_fold(const float* __restrict__ bih, const float* __restrict__ bhh,
                          float* __restrict__ bsum) {
    int i = blockIdx.x * blockDim.x + threadIdx.x;
    if (i < 768) bsum[i] = bih[i] + (i < 512 ? bhh[i] : 0.f);
}

// ---------------- pack W_hh [768,256] into MFMA B-frag order ----------------
// Wp[((jt*8 + kt)*64 + lane)*8 + i] = Whh[jt*16 + (lane&15)][kt*32 + (lane>>4)*8 + i]
__global__ void pack_whh(const float* __restrict__ W, u16* __restrict__ Wp) {
    int t = blockIdx.x * blockDim.x + threadIdx.x;   // 0..24575
    int l = t & 63;
    int kt = (t >> 6) & 7;
    int jt = t >> 9;                                  // 0..47
    int j = jt * 16 + (l & 15);
    int k = kt * 32 + (l >> 4) * 8;
    f16x8 o;
#pragma unroll
    for (int i = 0; i < 8; ++i) o[i] = (_Float16)W[j * 256 + k + i];
    *(f16x8*)(Wp + (size_t)t * 8) = o;
}

// ---------------- pack W2b [18,512] zero-padded to [32,512] in B-frag order --
__global__ void pack_w2b(const float* __restrict__ W, u16* __restrict__ Wp) {
    int t = blockIdx.x * blockDim.x + threadIdx.x;   // 0..2047
    int l = t & 63;
    int kt = (t >> 6) & 15;
    int nt = t >> 10;                                 // 0..1
    int n = nt * 16 + (l & 15);
    int k = kt * 32 + (l >> 4) * 8;
    f16x8 o;
#pragma unroll
    for (int i = 0; i < 8; ++i)
        o[i] = (n < 18) ? (_Float16)W[n * 512 + k + i] : (_Float16)0.f;
    *(f16x8*)(Wp + (size_t)t * 8) = o;
}

// ---------------- generic fp16 GEMM: C[m,n] = act(sum_k A[m,k]*B[n,k] + bias[n])
__global__ __launch_bounds__(256) void gemm_bt(
    const u16* __restrict__ A, const u16* __restrict__ B,
    const float* __restrict__ bias, u16* __restrict__ C,
    int N, int K, int act)
{
    __shared__ u16 Ash[4096] __attribute__((aligned(16)));
    __shared__ u16 Bsh[4096] __attribute__((aligned(16)));
    const int tid = threadIdx.x;
    const int l = tid & 63, w = tid >> 6;
    const long m0 = (long)blockIdx.y * 128;
    const int n0 = blockIdx.x * 128;
    const int r = tid >> 2, c8 = (tid & 3) * 8;
    const u16* gA0 = A + (m0 + r) * K + c8;
    const u16* gA1 = A + (m0 + 64 + r) * K + c8;
    const u16* gB0 = B + (long)(n0 + r) * K + c8;
    const u16* gB1 = B + (long)(n0 + 64 + r) * K + c8;
    const int mb = (w >> 1) * 64, nb = (w & 1) * 64;
    const int mrow = l & 15, colq = (l >> 4) * 8;
    fv4 acc[4][4] = {};
    for (int k0 = 0; k0 < K; k0 += 32) {
        gl_lds16(gA0 + k0, &Ash[tid * 8]);
        gl_lds16(gA1 + k0, &Ash[2048 + tid * 8]);
        gl_lds16(gB0 + k0, &Bsh[tid * 8]);
        gl_lds16(gB1 + k0, &Bsh[2048 + tid * 8]);
        __syncthreads();
        f16x8 af[4], bf[4];
#pragma unroll
        for (int i = 0; i < 4; ++i)
            af[i] = *(const f16x8*)&Ash[(mb + i * 16 + mrow) * 32 + colq];
#pragma unroll
        for (int i = 0; i < 4; ++i)
            bf[i] = *(const f16x8*)&Bsh[(nb + i * 16 + mrow) * 32 + colq];
#pragma unroll
        for (int mt = 0; mt < 4; ++mt)
#pragma unroll
            for (int nt = 0; nt < 4; ++nt)
                acc[mt][nt] = __builtin_amdgcn_mfma_f32_16x16x32_f16(
                    af[mt], bf[nt], acc[mt][nt], 0, 0, 0);
        __syncthreads();
    }
    float bv[4];
#pragma unroll
    for (int nt = 0; nt < 4; ++nt) bv[nt] = bias[n0 + nb + nt * 16 + mrow];
    const int rq = (l >> 4) * 4;
#pragma unroll
    for (int mt = 0; mt < 4; ++mt)
#pragma unroll
        for (int nt = 0; nt < 4; ++nt)
#pragma unroll
            for (int i = 0; i < 4; ++i) {
                float v = acc[mt][nt][i] + bv[nt];
                if (act) v = fmaxf(v, 0.f);
                C[(m0 + mb + mt * 16 + rq + i) * (long)N + (n0 + nb + nt * 16 + mrow)] = f2us(v);
            }
}

// ---------------- GI GEMM (N=768, K=256): stores into gru-packed layout -------
// GIp[((((t*16+blk)*8 + w)*64 + lane)*24 + u*4 + i] ; u = gate*2 + s
__global__ __launch_bounds__(256) void gemm_gi(
    const u16* __restrict__ A, const u16* __restrict__ B,
    const float* __restrict__ bias, u16* __restrict__ GIp)
{
    __shared__ u16 Ash[4096] __attribute__((aligned(16)));
    __shared__ u16 Bsh[4096] __attribute__((aligned(16)));
    const int tid = threadIdx.x;
    const int l = tid & 63, w = tid >> 6;
    const long m0 = (long)blockIdx.y * 128;
    const int n0 = blockIdx.x * 128;
    const int r = tid >> 2, c8 = (tid & 3) * 8;
    const u16* gA0 = A + (m0 + r) * 256 + c8;
    const u16* gA1 = A + (m0 + 64 + r) * 256 + c8;
    const u16* gB0 = B + (long)(n0 + r) * 256 + c8;
    const u16* gB1 = B + (long)(n0 + 64 + r) * 256 + c8;
    const int mb = (w >> 1) * 64, nb = (w & 1) * 64;
    const int mrow = l & 15, colq = (l >> 4) * 8;
    fv4 acc[4][4] = {};
    for (int k0 = 0; k0 < 256; k0 += 32) {
        gl_lds16(gA0 + k0, &Ash[tid * 8]);
        gl_lds16(gA1 + k0, &Ash[2048 + tid * 8]);
        gl_lds16(gB0 + k0, &Bsh[tid * 8]);
        gl_lds16(gB1 + k0, &Bsh[2048 + tid * 8]);
        __syncthreads();
        f16x8 af[4], bf[4];
#pragma unroll
        for (int i = 0; i < 4; ++i)
            af[i] = *(const f16x8*)&Ash[(mb + i * 16 + mrow) * 32 + colq];
#pragma unroll
        for (int i = 0; i < 4; ++i)
            bf[i] = *(const f16x8*)&Bsh[(nb + i * 16 + mrow) * 32 + colq];
#pragma unroll
        for (int mt = 0; mt < 4; ++mt)
#pragma unroll
            for (int nt = 0; nt < 4; ++nt)
                acc[mt][nt] = __builtin_amdgcn_mfma_f32_16x16x32_f16(
                    af[mt], bf[nt], acc[mt][nt], 0, 0, 0);
        __syncthreads();
    }
    float bv[4];
#pragma unroll
    for (int nt = 0; nt < 4; ++nt) bv[nt] = bias[n0 + nb + nt * 16 + mrow];
    const int rq = (l >> 4) * 4;
#pragma unroll
    for (int mt = 0; mt < 4; ++mt)
#pragma unroll
        for (int nt = 0; nt < 4; ++nt)
#pragma unroll
            for (int i = 0; i < 4; ++i) {
                float v = acc[mt][nt][i] + bv[nt];
                int m = (int)(m0 + mb + mt * 16 + rq + i);
                int n = n0 + nb + nt * 16 + mrow;
                int t  = m >> 8, b = m & 255;
                int blk = b >> 4, rb = b & 15, q = rb >> 2, i2 = rb & 3;
                int g = n >> 8, c = n & 255, w2 = c >> 5, s = (c >> 4) & 1, cl = c & 15;
                size_t idx = ((((size_t)t * 16 + blk) * 8 + w2) * 64 + (q * 16 + cl)) * 24
                             + (g * 2 + s) * 4 + i2;
                GIp[idx] = f2us(v);
            }
}

// ---------------- sequential GRU v7: 16 waves, fits the 128-VGPR budget -------
// Rounds 0-3 evidence: the RA gives this kernel a 128-VGPR budget no matter
// what we declare; 8-wave x 6-jt needs 192 VGPRs of W frags -> sink (v4) or
// spill (v5) or fail (v6 attr). v7 restructures: 16 waves x 3 jt each.
//   regs: wf[3][6] = 18 frags = 72 VGPR (kt 0..5), acc 12, gi 12 -> ~124 total
//   LDS:  kt 6,7 in Wl (96KB) + h dbuf (16KB) = 112KB (1 block/CU, 4 waves/EU)
// No pins, no occupancy attributes: the fragments fit, so the RA keeps them.
// Epilogue: 4 values/lane (vs 8), cheap tanh = 1-2/(e^{2x}+1).
// Verification: VGPR_Count <=128, no scratch, dur ~420-520us (vs 850).
__global__ __launch_bounds__(1024) void gru_seq7(
    const u16* __restrict__ Wp, const u16* __restrict__ GIp,
    const float* __restrict__ bhh, u16* __restrict__ Hp)
{
    __shared__ u16 h_sh[2][4096] __attribute__((aligned(16)));  // dbuf h (A-frag layout)
    __shared__ u16 Wl[49152] __attribute__((aligned(16)));      // kt 6,7: [2][48][64][8]
    const int tid = threadIdx.x;
    const int l = tid & 63, w = tid >> 6;        // w = 0..15
    const int blk = blockIdx.x;
    const int col = l & 15, quad = l >> 4;

    for (int i = tid; i < 4096; i += 1024) h_sh[0][i] = 0;
    for (int idx = tid; idx < 6144; idx += 1024) {
        int kt6 = idx / 3072, rem = idx % 3072;   // jt = rem>>6, lane = rem&63
        *(f16x8*)&Wl[(size_t)idx * 8] =
            *(const f16x8*)&Wp[(((size_t)(rem >> 6) * 8 + 6 + kt6) * 64 + (rem & 63)) * 8];
    }

    const int jt0 = w, jt1 = 16 + w, jt2 = 32 + w;   // gates r, z, n

    // W_hh fragments kt 0..5: 18 f16x8 = 72 VGPRs, loop-invariant, fits budget.
    f16x8 wf[3][6];
    {
        const int jts[3] = { jt0, jt1, jt2 };
#pragma unroll
        for (int g = 0; g < 3; ++g)
#pragma unroll
            for (int kt = 0; kt < 6; ++kt)
                wf[g][kt] = *(const f16x8*)&Wp[(((size_t)jts[g] * 8 + kt) * 64 + l) * 8];
    }

    const int c = 16 * w + col;                  // this lane's h column
    const float hbn = bhh[512 + c];

    // gi: lane needs rows quad*4+i, col c, gates 0..2 -> 3 x 8B chunks
    const u16* gbase = GIp + ((size_t)(blk * 8 + (w >> 1)) * 64 + l) * 24 + (w & 1) * 4;
    f16x4 gcur[3], gnxt[3];
#pragma unroll
    for (int g = 0; g < 3; ++g) gcur[g] = *(const f16x4*)(gbase + g * 8);

    float hold[4] = {};
    u16* hp_base = Hp + (size_t)blk * 4096 + tid * 8;   // packed A-frag layout (tid<512)
    // h_sh write slot: row = quad*4+i, col c -> A-frag addr (derivation in notes)
    const int wbase = ((w >> 1) * 64 + ((2 * w + (col >> 3)) & 3) * 16 + quad * 4) * 8 + (col & 7);
    __syncthreads();

    for (int t = 0; t < TT; ++t) {
        const int rd = t & 1, wr = (t + 1) & 1;
        // store h_t (finished last step) as one 16B packed store; Hout[t-1] = h_t
        if (t && tid < 512) {
            f16x8 hv = *(const f16x8*)&h_sh[rd][tid * 8];
            *(f16x8*)(hp_base + (size_t)(t - 1) * 65536) = hv;
        }
        // prefetch next step's gi (full step of latency cover)
        const u16* gn = gbase + (size_t)(t < TT - 1 ? t + 1 : t) * 196608;
#pragma unroll
        for (int g = 0; g < 3; ++g) gnxt[g] = *(const f16x4*)(gn + g * 8);

        fv4 acc[3] = {};
#pragma unroll
        for (int kt = 0; kt < 6; ++kt) {
            f16x8 a = *(const f16x8*)&h_sh[rd][(kt * 64 + l) * 8];
            acc[0] = __builtin_amdgcn_mfma_f32_16x16x32_f16(a, wf[0][kt], acc[0], 0, 0, 0);
            acc[1] = __builtin_amdgcn_mfma_f32_16x16x32_f16(a, wf[1][kt], acc[1], 0, 0, 0);
            acc[2] = __builtin_amdgcn_mfma_f32_16x16x32_f16(a, wf[2][kt], acc[2], 0, 0, 0);
        }
#pragma unroll
        for (int kt6 = 0; kt6 < 2; ++kt6) {
            f16x8 a = *(const f16x8*)&h_sh[rd][((6 + kt6) * 64 + l) * 8];
            f16x8 b0 = *(const f16x8*)&Wl[((size_t)(kt6 * 48 + jt0) * 64 + l) * 8];
            f16x8 b1 = *(const f16x8*)&Wl[((size_t)(kt6 * 48 + jt1) * 64 + l) * 8];
            f16x8 b2 = *(const f16x8*)&Wl[((size_t)(kt6 * 48 + jt2) * 64 + l) * 8];
            acc[0] = __builtin_amdgcn_mfma_f32_16x16x32_f16(a, b0, acc[0], 0, 0, 0);
            acc[1] = __builtin_amdgcn_mfma_f32_16x16x32_f16(a, b1, acc[1], 0, 0, 0);
            acc[2] = __builtin_amdgcn_mfma_f32_16x16x32_f16(a, b2, acc[2], 0, 0, 0);
        }
        // epilogue: gates + h update (writes OTHER h buffer -> one barrier/step)
#pragma unroll
        for (int i = 0; i < 4; ++i) {
            float pr  = (float)gcur[0][i] + acc[0][i];   // bias folded into gi
            float pz  = (float)gcur[1][i] + acc[1][i];
            float hnp = acc[2][i] + hbn;
            float rg = __builtin_amdgcn_rcpf(1.f + __expf(-pr));
            float zg = __builtin_amdgcn_rcpf(1.f + __expf(-pz));
            float pre = (float)gcur[2][i] + rg * hnp;
            float e2 = __expf(2.f * pre);                // inf-safe: rcp(inf)=0
            float ng = 1.f - 2.f * __builtin_amdgcn_rcpf(e2 + 1.f);
            float hn = ng + zg * (hold[i] - ng);         // (1-z)n + z*h
            hold[i] = hn;
            h_sh[wr][wbase + i * 8] = f2us(hn);
        }
#pragma unroll
        for (int g = 0; g < 3; ++g) gcur[g] = gnxt[g];
        __syncthreads();
    }
    // final h_512 lives in buffer (TT)&1 == 0 -> Hout[511]
    if (tid < 512) {
        f16x8 hv = *(const f16x8*)&h_sh[0][tid * 8];
        *(f16x8*)(hp_base + (size_t)511 * 65536) = hv;
    }
}

// ---------------- Phase-B GEMM from packed Hp: C = relu(Hp @ W2a^T + b2a) -----
// A-fragments come straight from global (already MFMA A-frag order), no A
// staging. B staged via gl_lds16 as usual. N=512, K=256 fixed.
__global__ __launch_bounds__(256) void gemm_hp(
    const u16* __restrict__ Hp, const u16* __restrict__ B,
    const float* __restrict__ bias, u16* __restrict__ C)
{
    __shared__ u16 Bsh[4096] __attribute__((aligned(16)));
    const int tid = threadIdx.x;
    const int l = tid & 63, w = tid >> 6;
    const long m0 = (long)blockIdx.y * 128;
    const int n0 = blockIdx.x * 128;
    const int r = tid >> 2, c8 = (tid & 3) * 8;
    const u16* gB0 = B + (long)(n0 + r) * 256 + c8;
    const u16* gB1 = B + (long)(n0 + 64 + r) * 256 + c8;
    const int mb = (w >> 1) * 64, nb = (w & 1) * 64;
    const int mrow = l & 15, colq = (l >> 4) * 8;
    const int t = (int)(m0 >> 8), half = ((int)m0 >> 7) & 1;
    // row-tile mt (16 rows) -> blk16 = half*8 + mb/16 + mt ; frag at [kt*64+l]*8
    const u16* aBase = Hp + ((size_t)t * 16 + half * 8 + (mb >> 4)) * 4096 + (size_t)l * 8;
    fv4 acc[4][4] = {};
    for (int k0 = 0; k0 < 256; k0 += 32) {
        gl_lds16(gB0 + k0, &Bsh[tid * 8]);
        gl_lds16(gB1 + k0, &Bsh[2048 + tid * 8]);
        const int kt = k0 >> 5;
        f16x8 af[4];
#pragma unroll
        for (int i = 0; i < 4; ++i)
            af[i] = *(const f16x8*)(aBase + (size_t)i * 4096 + kt * 512);
        __syncthreads();
        f16x8 bf[4];
#pragma unroll
        for (int i = 0; i < 4; ++i)
            bf[i] = *(const f16x8*)&Bsh[(nb + i * 16 + mrow) * 32 + colq];
#pragma unroll
        for (int mt = 0; mt < 4; ++mt)
#pragma unroll
            for (int nt = 0; nt < 4; ++nt)
                acc[mt][nt] = __builtin_amdgcn_mfma_f32_16x16x32_f16(
                    af[mt], bf[nt], acc[mt][nt], 0, 0, 0);
        __syncthreads();
    }
    float bv[4];
#pragma unroll
    for (int nt = 0; nt < 4; ++nt) bv[nt] = bias[n0 + nb + nt * 16 + mrow];
    const int rq = (l >> 4) * 4;
#pragma unroll
    for (int mt = 0; mt < 4; ++mt)
#pragma unroll
        for (int nt = 0; nt < 4; ++nt)
#pragma unroll
            for (int i = 0; i < 4; ++i) {
                float v = fmaxf(acc[mt][nt][i] + bv[nt], 0.f);
                C[(m0 + mb + mt * 16 + rq + i) * 512L + (n0 + nb + nt * 16 + mrow)] = f2us(v);
            }
}

// ---------------- head: out[m, 0..17] = Q1[m,:512] @ W2b^T + b2b (fp32 out) ---
__global__ __launch_bounds__(256) void head_gemm(
    const u16* __restrict__ Q1, const u16* __restrict__ W2p,
    const float* __restrict__ b2, float* __restrict__ out)
{
    __shared__ u16 Ash[4096] __attribute__((aligned(16)));
    __shared__ u16 Bsh[16384] __attribute__((aligned(16)));
    const int tid = threadIdx.x;
    const int l = tid & 63, w = tid >> 6;
    const long m0 = (long)blockIdx.x * 128;
    const int col = l & 15, quad = l >> 4, colq = quad * 8;
    for (int i = tid * 8; i < 16384; i += 2048)
        *(f16x8*)&Bsh[i] = *(const f16x8*)&W2p[i];
    const int r = tid >> 2, c8 = (tid & 3) * 8;
    const u16* gA0 = Q1 + (m0 + r) * 512 + c8;
    const u16* gA1 = Q1 + (m0 + 64 + r) * 512 + c8;
    fv4 acc[2][2] = {};
    for (int k0 = 0; k0 < 512; k0 += 32) {
        gl_lds16(gA0 + k0, &Ash[tid * 8]);
        gl_lds16(gA1 + k0, &Ash[2048 + tid * 8]);
        __syncthreads();
        const int kt = k0 >> 5;
        f16x8 af[2], bf[2];
#pragma unroll
        for (int mt = 0; mt < 2; ++mt)
            af[mt] = *(const f16x8*)&Ash[(w * 32 + mt * 16 + col) * 32 + colq];
#pragma unroll
        for (int nt = 0; nt < 2; ++nt)
            bf[nt] = *(const f16x8*)&Bsh[((nt * 16 + kt) * 64 + l) * 8];
#pragma unroll
        for (int mt = 0; mt < 2; ++mt)
#pragma unroll
            for (int nt = 0; nt < 2; ++nt)
                acc[mt][nt] = __builtin_amdgcn_mfma_f32_16x16x32_f16(
                    af[mt], bf[nt], acc[mt][nt], 0, 0, 0);
        __syncthreads();
    }
    const int rq = quad * 4;
#pragma unroll
    for (int nt = 0; nt < 2; ++nt) {
        int c = nt * 16 + col;
        if (c < 18) {
            float bias = b2[c];
#pragma unroll
            for (int mt = 0; mt < 2; ++mt)
#pragma unroll
                for (int i = 0; i < 4; ++i)
                    out[(m0 + w * 32 + mt * 16 + rq + i) * 18 + c] = acc[mt][nt][i] + bias;
        }
    }
}

extern "C" void kernel_launch(void* const* d_in, const int* in_sizes, int n_in,
                              void* d_out, int out_size, void* d_ws, size_t ws_size,
                              hipStream_t stream) {
    const float* x   = (const float*)d_in[0];
    const float* W1a = (const float*)d_in[1];
    const float* b1a = (const float*)d_in[2];
    const float* W1b = (const float*)d_in[3];
    const float* b1b = (const float*)d_in[4];
    const float* Wih = (const float*)d_in[5];
    const float* bih = (const float*)d_in[6];
    const float* Whh = (const float*)d_in[7];
    const float* bhh = (const float*)d_in[8];
    const float* W2a = (const float*)d_in[9];
    const float* b2a = (const float*)d_in[10];
    const float* W2b = (const float*)d_in[11];
    const float* b2b = (const float*)d_in[12];

    char* ws = (char*)d_ws;
    u16* R    = (u16*)ws;                 // A1 [131072,512]f16, then GIp packed
    u16* A2b  = (u16*)(ws + 201326592);   // 67108864 B
    u16* XH   = (u16*)(ws + 268435456);   // 67108864 B (x fp16, later Hp packed)
    float* bsum = (float*)(ws + 268435456 + 67108864 - 4096);
    u16* W1ah = (u16*)(ws + 335544320);   //   262144 B
    u16* W1bh = (u16*)(ws + 335806464);   //   262144 B
    u16* Wihh = (u16*)(ws + 336068608);   //   393216 B
    u16* W2ah = (u16*)(ws + 336461824);   //   262144 B
    u16* Wpk  = (u16*)(ws + 336723968);   //   393216 B
    u16* W2p  = (u16*)(ws + 337117184);   //    32768 B
    if (ws_size < 337149952) {
        fprintf(stderr, "kernel_launch: ws too small (%zu < 337149952)\n", ws_size);
    }

    cvt_f32_f16<<<dim3(2048), dim3(256), 0, stream>>>(x, XH, 33554432);
    cvt_f32_f16<<<dim3(64), dim3(256), 0, stream>>>(W1a, W1ah, 131072);
    cvt_f32_f16<<<dim3(64), dim3(256), 0, stream>>>(W1b, W1bh, 131072);
    cvt_f32_f16<<<dim3(96), dim3(256), 0, stream>>>(Wih, Wihh, 196608);
    cvt_f32_f16<<<dim3(64), dim3(256), 0, stream>>>(W2a, W2ah, 131072);
    pack_whh<<<dim3(96), dim3(256), 0, stream>>>(Whh, Wpk);
    pack_w2b<<<dim3(8), dim3(256), 0, stream>>>(W2b, W2p);

    // Phase A
    gemm_bt<<<dim3(4, 1024), dim3(256), 0, stream>>>(XH, W1ah, b1a, R,   512, 256, 1);
    bias_fold<<<dim3(3), dim3(256), 0, stream>>>(bih, bhh, bsum);
    gemm_bt<<<dim3(2, 1024), dim3(256), 0, stream>>>(R,  W1bh, b1b, A2b, 256, 512, 1);
    gemm_gi<<<dim3(6, 1024), dim3(256), 0, stream>>>(A2b, Wihh, bsum, R);
    // Phase R: sequential GRU (writes Hp packed A-frag layout into XH region)
    gru_seq7<<<dim3(16), dim3(1024), 0, stream>>>(Wpk, R, bhh, XH);
    // Phase B
    gemm_hp<<<dim3(4, 1024), dim3(256), 0, stream>>>(XH, W2ah, b2a, R);
    head_gemm<<<dim3(1024), dim3(256), 0, stream>>>(R, W2p, b2b, (float*)d_out);
}